// Round 12
// baseline (247.054 us; speedup 1.0000x reference)
//
#include <hip/hip_runtime.h>
#include <hip/hip_bf16.h>
#include <hip/hip_fp16.h>
#include <stdint.h>

typedef __bf16 bf16_t;
typedef __bf16 bf16x8 __attribute__((ext_vector_type(8)));
typedef float f32x4 __attribute__((ext_vector_type(4)));

typedef __attribute__((address_space(1))) void gv_t;
typedef __attribute__((address_space(3))) void lv_t;

__device__ inline unsigned short f2bf_bits(float f) {
  uint32_t u = __float_as_uint(f);
  u += 0x7FFFu + ((u >> 16) & 1u);   // RNE
  return (unsigned short)(u >> 16);
}
__device__ inline bf16_t f2bf(float f) {
  unsigned short h = f2bf_bits(f);
  return __builtin_bit_cast(bf16_t, h);
}

__device__ inline void storeC(float* p, float v) { *p = v; }
__device__ inline void storeC(bf16_t* p, float v) { *p = f2bf(v); }
__device__ inline void storeC(__half* p, float v) { *p = __float2half(v); }

// ---------------------------------------------------------------------------
// fp32 -> bf16 conversion for x, Wq, Wk (packed together), Wv
// ---------------------------------------------------------------------------
__global__ __launch_bounds__(256)
void convert_all(const float* __restrict__ x, const float* __restrict__ wq,
                 const float* __restrict__ wk, const float* __restrict__ wv,
                 bf16_t* __restrict__ xb, bf16_t* __restrict__ wqkb,
                 bf16_t* __restrict__ wvb)
{
  const int64_t NX = 8192LL * 1024, NW = 1024LL * 1024;
  const int64_t total4 = (NX + 3 * NW) >> 2;
  for (int64_t i = (int64_t)blockIdx.x * blockDim.x + threadIdx.x; i < total4;
       i += (int64_t)gridDim.x * blockDim.x) {
    int64_t e = i << 2;
    const float* src; bf16_t* dst; int64_t off;
    if (e < NX)               { src = x;  dst = xb;         off = e; }
    else if (e < NX + NW)     { src = wq; dst = wqkb;       off = e - NX; }
    else if (e < NX + 2 * NW) { src = wk; dst = wqkb + NW;  off = e - NX - NW; }
    else                      { src = wv; dst = wvb;        off = e - NX - 2 * NW; }
    float4 f = *(const float4*)(src + off);
    uint32_t lo = ((uint32_t)f2bf_bits(f.y) << 16) | f2bf_bits(f.x);
    uint32_t hi = ((uint32_t)f2bf_bits(f.w) << 16) | f2bf_bits(f.z);
    *(uint2*)(dst + off) = make_uint2(lo, hi);
  }
}

// ---------------------------------------------------------------------------
// 256x128 bf16 GEMM, 1-barrier-per-K-tile + 3-buffer COUNTED-vmcnt pipeline
// (R12). BK=64, 8 waves (4M x 2N), per-wave 64x64 = acc[4][4] of 16x16x32.
// LDS 144 KiB: As[3][256][64] (96K) + Bs[3][128][64] (48K), XOR swizzle
// byte^=((row&7)<<4) via pre-swizzled global source + swizzled ds_read.
//
// T4 realized in the winning R8 structure: tile g stages tile g+2 into
// buf[(g+2)%3] (6 global_load_lds per wave: A 4 x 64-row slabs, B 2); the
// end-of-tile gate is vmcnt(6) — retires exactly tile g+1's loads (issued
// one FULL tile earlier, ~several-thousand cyc of slack, so the gate never
// stalls) while tile g+2's 6 float across the barrier. Drain vmcnt(0) only
// in the last two tiles. WAR: buf[(g+2)%3] == buf[(g-1)%3], last read in
// tile g-1, fenced by that tile's closing barrier. RAW: tile g's buf was
// retired by the end-of-(g-1) gate, before every wave's barrier.
// blockIdx.z split-K: z=0 -> C0, z=1 -> C1. Bb = B + (bm/bm_per_batch)*bbs.
// ---------------------------------------------------------------------------
template <typename OUT_T, typename OUT2_T>
__global__ __launch_bounds__(512, 2)
void gemm3(const bf16_t* __restrict__ A, const bf16_t* __restrict__ B,
           OUT_T* __restrict__ C0, OUT2_T* __restrict__ C1,
           int K, int lda, int ldb, int ldc,
           int64_t b_batch_stride, int bm_per_batch,
           int64_t za_off, int64_t zb_off)
{
  __shared__ bf16_t As[3][256][64];
  __shared__ bf16_t Bs[3][128][64];

  const int tid  = threadIdx.x;
  const int wid  = tid >> 6;     // 0..7
  const int lane = tid & 63;
  const int wm = wid >> 1;       // 0..3 -> 64-row panel
  const int wn = wid & 1;        // 0..1 -> 64-col panel
  const int64_t bm = blockIdx.x;
  const int64_t bn = blockIdx.y;
  const int z = blockIdx.z;

  const bf16_t* Ap = A + (int64_t)z * za_off;
  const bf16_t* Bp = B + (bm / bm_per_batch) * b_batch_stride
                       + (int64_t)z * zb_off;

  // staging: one gload instr = 512 thr x 16 B = 64 rows of 128 B.
  // thread -> row tid>>3 (0..63), slot tid&7; source slot pre-swizzled.
  const int srow  = tid >> 3;
  const int sslot = (tid & 7) ^ (srow & 7);
  const int64_t lda64 = lda, ldb64 = ldb;
  const bf16_t* Ag = Ap + (bm * 256 + srow) * lda64 + sslot * 8;
  const bf16_t* Bg = Bp + (bn * 128 + srow) * ldb64 + sslot * 8;

  // q-th 64-row slab of tile t -> LDS buf (wave w owns rows q*64+w*8..+8)
  auto stageA = [&](int buf, int t, int q) {
    const bf16_t* src = Ag + (int64_t)(q * 64) * lda64 + t * 64;
    char* dst = (char*)&As[buf][0][0] + (q * 64 + wid * 8) * 128;
    __builtin_amdgcn_global_load_lds((const gv_t*)src, (lv_t*)dst, 16, 0, 0);
  };
  auto stageB = [&](int buf, int t, int q) {
    const bf16_t* src = Bg + (int64_t)(q * 64) * ldb64 + t * 64;
    char* dst = (char*)&Bs[buf][0][0] + (q * 64 + wid * 8) * 128;
    __builtin_amdgcn_global_load_lds((const gv_t*)src, (lv_t*)dst, 16, 0, 0);
  };
  auto stageTile = [&](int buf, int t) {   // 6 loads/wave
    stageA(buf, t, 0); stageA(buf, t, 1);
    stageA(buf, t, 2); stageA(buf, t, 3);
    stageB(buf, t, 0); stageB(buf, t, 1);
  };

  // fragment read coords (swizzled): row&7 == lane&7 for all frags
  const int frow   = lane & 15;
  const int fcol16 = lane >> 4;
  const int xorv   = (lane & 7) << 4;
  const int ck0 = (fcol16 * 16) ^ xorv;       // k 0..31 byte col
  const int ck1 = (64 + fcol16 * 16) ^ xorv;  // k 32..63
  const int arowb = (wm * 64 + frow) * 128;
  const int browb = (wn * 64 + frow) * 128;

  f32x4 acc[4][4];
  #pragma unroll
  for (int m = 0; m < 4; m++)
    #pragma unroll
    for (int n = 0; n < 4; n++) acc[m][n] = f32x4{0.f, 0.f, 0.f, 0.f};

  const int NT = K >> 6;

  // prologue: stage T0 -> buf0, T1 -> buf1; gate retires T0 (6 in flight)
  stageTile(0, 0);
  if (1 < NT) {
    stageTile(1, 1);
    asm volatile("s_waitcnt vmcnt(6)" ::: "memory");
  } else {
    asm volatile("s_waitcnt vmcnt(0)" ::: "memory");
  }
  __builtin_amdgcn_s_barrier();
  __builtin_amdgcn_sched_barrier(0);

  bf16x8 a[4][2], bb[4][2];

  for (int g = 0; g < NT; ++g) {
    const int buf = g % 3;
    const char* lA = (const char*)&As[buf][0][0];
    const char* lB = (const char*)&Bs[buf][0][0];

    // ---- 16 frag reads, k0 first (k1 drains under k0 MFMAs) ----
    #pragma unroll
    for (int m = 0; m < 4; m++)
      a[m][0] = *(const bf16x8*)(lA + arowb + m * 2048 + ck0);
    #pragma unroll
    for (int n = 0; n < 4; n++)
      bb[n][0] = *(const bf16x8*)(lB + browb + n * 2048 + ck0);
    #pragma unroll
    for (int m = 0; m < 4; m++)
      a[m][1] = *(const bf16x8*)(lA + arowb + m * 2048 + ck1);
    #pragma unroll
    for (int n = 0; n < 4; n++)
      bb[n][1] = *(const bf16x8*)(lB + browb + n * 2048 + ck1);

    // ---- stage tile g+2 into buf[(g+2)%3] (WAR-safe, see header) ----
    if (g + 2 < NT) stageTile((g + 2) % 3, g + 2);

    // ---- 32 MFMAs; compiler-counted lgkm overlaps reads under burst ----
    __builtin_amdgcn_s_setprio(1);
    #pragma unroll
    for (int k = 0; k < 2; k++)
      #pragma unroll
      for (int m = 0; m < 4; m++)
        #pragma unroll
        for (int n = 0; n < 4; n++)
          acc[m][n] = __builtin_amdgcn_mfma_f32_16x16x32_bf16(
              a[m][k], bb[n][k], acc[m][n], 0, 0, 0);
    __builtin_amdgcn_s_setprio(0);

    // ---- counted gate: retire tile g+1's loads, keep g+2's in flight ----
    if (g + 2 < NT) {
      asm volatile("s_waitcnt vmcnt(6)" ::: "memory");
    } else {
      asm volatile("s_waitcnt vmcnt(0)" ::: "memory");
    }
    __builtin_amdgcn_s_barrier();
    __builtin_amdgcn_sched_barrier(0);
  }

  // epilogue: C/D layout col=lane&15, row=(lane>>4)*4+j
  const int crow = (lane >> 4) * 4;
  const int ccol = lane & 15;
  if (z == 0) {
    #pragma unroll
    for (int m = 0; m < 4; m++)
      #pragma unroll
      for (int n = 0; n < 4; n++)
        #pragma unroll
        for (int j = 0; j < 4; j++) {
          int64_t row = bm * 256 + wm * 64 + m * 16 + crow + j;
          int64_t col = bn * 128 + wn * 64 + n * 16 + ccol;
          storeC(&C0[row * (int64_t)ldc + col], acc[m][n][j]);
        }
  } else {
    #pragma unroll
    for (int m = 0; m < 4; m++)
      #pragma unroll
      for (int n = 0; n < 4; n++)
        #pragma unroll
        for (int j = 0; j < 4; j++) {
          int64_t row = bm * 256 + wm * 64 + m * 16 + crow + j;
          int64_t col = bn * 128 + wn * 64 + n * 16 + ccol;
          storeC(&C1[row * (int64_t)ldc + col], acc[m][n][j]);
        }
  }
}

// ---------------------------------------------------------------------------
// Row softmax IN PLACE: fp16 raw scores [rows x 4096] -> normalized bf16 P.
// ---------------------------------------------------------------------------
__global__ __launch_bounds__(256)
void softmax_rows(__half* __restrict__ SP)
{
  const int64_t row = blockIdx.x;
  __half* s = SP + row * 4096;
  bf16_t* p = (bf16_t*)s;
  const int tid = threadIdx.x;
  const float scale = 0.03125f;  // 1/sqrt(1024)

  float v[16];
  float vmax = -3.4e38f;
  #pragma unroll
  for (int i = 0; i < 4; i++) {
    uint2 raw = *(const uint2*)(s + i * 1024 + tid * 4);
    __half2 h01 = __builtin_bit_cast(__half2, raw.x);
    __half2 h23 = __builtin_bit_cast(__half2, raw.y);
    float2 f01 = __half22float2(h01);
    float2 f23 = __half22float2(h23);
    v[i * 4 + 0] = f01.x * scale;
    v[i * 4 + 1] = f01.y * scale;
    v[i * 4 + 2] = f23.x * scale;
    v[i * 4 + 3] = f23.y * scale;
    vmax = fmaxf(vmax, fmaxf(fmaxf(v[i*4+0], v[i*4+1]),
                             fmaxf(v[i*4+2], v[i*4+3])));
  }
  #pragma unroll
  for (int o = 32; o > 0; o >>= 1) vmax = fmaxf(vmax, __shfl_xor(vmax, o));
  __shared__ float redm[4];
  __shared__ float reds[4];
  if ((tid & 63) == 0) redm[tid >> 6] = vmax;
  __syncthreads();
  vmax = fmaxf(fmaxf(redm[0], redm[1]), fmaxf(redm[2], redm[3]));

  float lsum = 0.f;
  #pragma unroll
  for (int i = 0; i < 16; i++) {
    v[i] = __expf(v[i] - vmax);
    lsum += v[i];
  }
  #pragma unroll
  for (int o = 32; o > 0; o >>= 1) lsum += __shfl_xor(lsum, o);
  if ((tid & 63) == 0) reds[tid >> 6] = lsum;
  __syncthreads();
  lsum = (reds[0] + reds[1]) + (reds[2] + reds[3]);
  const float inv = 1.0f / lsum;

  #pragma unroll
  for (int i = 0; i < 4; i++) {
    uint32_t lo = ((uint32_t)f2bf_bits(v[i*4+1] * inv) << 16) | f2bf_bits(v[i*4+0] * inv);
    uint32_t hi = ((uint32_t)f2bf_bits(v[i*4+3] * inv) << 16) | f2bf_bits(v[i*4+2] * inv);
    *(uint2*)(p + i * 1024 + tid * 4) = make_uint2(lo, hi);
  }
}

// ---------------------------------------------------------------------------
// out[i] += (float)partial_fp16[i]  (split-K reduce)
// ---------------------------------------------------------------------------
__global__ __launch_bounds__(256)
void addk_h4(float4* __restrict__ o, const uint2* __restrict__ a, int64_t n4)
{
  for (int64_t i = (int64_t)blockIdx.x * blockDim.x + threadIdx.x; i < n4;
       i += (int64_t)gridDim.x * blockDim.x) {
    float4 x = o[i];
    uint2 raw = a[i];
    __half2 h01 = __builtin_bit_cast(__half2, raw.x);
    __half2 h23 = __builtin_bit_cast(__half2, raw.y);
    float2 f01 = __half22float2(h01);
    float2 f23 = __half22float2(h23);
    x.x += f01.x; x.y += f01.y; x.z += f23.x; x.w += f23.y;
    o[i] = x;
  }
}

// ---------------------------------------------------------------------------
// ws layout (112 MiB):
//   [0,   64M): S/P fp16->bf16 [8192 x 4096]
//               overlapped early: xb [0,16M), wqkb [16M,20M), wvb [20M,22M)
//   [64M, 96M): qk bf16 [8192 x 2048] (Q|K); dead after S -> reused as
//               PV fp16 split-K partial pk16 [8192 x 1024] (16 MiB)
//   [96M,112M): vt bf16 [1024 x 8192]
// ---------------------------------------------------------------------------
extern "C" void kernel_launch(void* const* d_in, const int* in_sizes, int n_in,
                              void* d_out, int out_size, void* d_ws, size_t ws_size,
                              hipStream_t stream) {
  const float* x  = (const float*)d_in[0];
  const float* wq = (const float*)d_in[1];
  const float* wk = (const float*)d_in[2];
  const float* wv = (const float*)d_in[3];
  float* out = (float*)d_out;

  char* ws = (char*)d_ws;
  bf16_t* xb   = (bf16_t*)ws;
  bf16_t* wqkb = (bf16_t*)(ws + (16LL << 20));
  bf16_t* wvb  = (bf16_t*)(ws + (20LL << 20));
  __half* S    = (__half*)ws;
  bf16_t* qk   = (bf16_t*)(ws + (64LL << 20));
  __half* pk16 = (__half*)(ws + (64LL << 20));  // PV split-K partial (16 MiB)
  bf16_t* vt   = (bf16_t*)(ws + (96LL << 20));

  const int NO_BATCH = 1 << 30;

  convert_all<<<2048, 256, 0, stream>>>(x, wq, wk, wv, xb, wqkb, wvb);

  // qk[8192 x 2048] = xb * wqkb^T   (grid 32x16 = 512 blocks)
  gemm3<bf16_t, bf16_t><<<dim3(32, 16, 1), 512, 0, stream>>>(
      xb, wqkb, qk, qk, 1024, 1024, 1024, 2048, 0, NO_BATCH, 0, 0);

  // vt[1024 x 8192] = wvb * xb^T   (grid 4x64 = 256 blocks)
  gemm3<bf16_t, bf16_t><<<dim3(4, 64, 1), 512, 0, stream>>>(
      wvb, xb, vt, vt, 1024, 1024, 1024, 8192, 0, NO_BATCH, 0, 0);

  // S[8192 x 4096] = Q * K_b^T (raw fp16), batch b = bm/16 (256-row tiles)
  gemm3<__half, __half><<<dim3(32, 32, 1), 512, 0, stream>>>(
      qk, qk + 1024, S, S, 1024, 2048, 2048, 4096, 4096LL * 2048, 16, 0, 0);

  softmax_rows<<<8192, 256, 0, stream>>>(S);

  // out[8192 x 1024] = P * V_b^T, split-K (z=0 -> out f32, z=1 -> pk16 fp16)
  gemm3<float, __half><<<dim3(32, 8, 2), 512, 0, stream>>>(
      (const bf16_t*)S, vt, out, pk16, 2048, 4096, 8192, 1024,
      4096, 16, 2048, 2048);

  addk_h4<<<2048, 256, 0, stream>>>((float4*)out, (const uint2*)pk16,
                                    8192LL * 1024 / 4);
}

// Round 13
// 216.741 us; speedup vs baseline: 1.1399x; 1.1399x over previous
//
#include <hip/hip_runtime.h>
#include <hip/hip_bf16.h>
#include <hip/hip_fp16.h>
#include <stdint.h>

typedef __bf16 bf16_t;
typedef __bf16 bf16x8 __attribute__((ext_vector_type(8)));
typedef float f32x4 __attribute__((ext_vector_type(4)));

typedef __attribute__((address_space(1))) void gv_t;
typedef __attribute__((address_space(3))) void lv_t;

__device__ inline unsigned short f2bf_bits(float f) {
  uint32_t u = __float_as_uint(f);
  u += 0x7FFFu + ((u >> 16) & 1u);   // RNE
  return (unsigned short)(u >> 16);
}
__device__ inline bf16_t f2bf(float f) {
  unsigned short h = f2bf_bits(f);
  return __builtin_bit_cast(bf16_t, h);
}

__device__ inline void storeC(float* p, float v) { *p = v; }
__device__ inline void storeC(bf16_t* p, float v) { *p = f2bf(v); }
__device__ inline void storeC(__half* p, float v) { *p = __float2half(v); }

// XCD-aware bijective remap (T1, m204-style; requires gridDim.x % 8 == 0).
// Consecutive same-XCD slots share bm (A panel) -> per-XCD L2 reuse.
__device__ inline void xcd_remap(int64_t& bm, int64_t& bn) {
  const int gx  = gridDim.x;
  const int h   = blockIdx.x + gx * blockIdx.y;
  const int gpx = gx >> 3;
  const int xcd = h & 7;
  const int s   = h >> 3;
  bm = xcd * gpx + (s % gpx);
  bn = s / gpx;
}

// ---------------------------------------------------------------------------
// fp32 -> bf16 conversion for x, Wq, Wk (packed together), Wv
// ---------------------------------------------------------------------------
__global__ __launch_bounds__(256)
void convert_all(const float* __restrict__ x, const float* __restrict__ wq,
                 const float* __restrict__ wk, const float* __restrict__ wv,
                 bf16_t* __restrict__ xb, bf16_t* __restrict__ wqkb,
                 bf16_t* __restrict__ wvb)
{
  const int64_t NX = 8192LL * 1024, NW = 1024LL * 1024;
  const int64_t total4 = (NX + 3 * NW) >> 2;
  for (int64_t i = (int64_t)blockIdx.x * blockDim.x + threadIdx.x; i < total4;
       i += (int64_t)gridDim.x * blockDim.x) {
    int64_t e = i << 2;
    const float* src; bf16_t* dst; int64_t off;
    if (e < NX)               { src = x;  dst = xb;         off = e; }
    else if (e < NX + NW)     { src = wq; dst = wqkb;       off = e - NX; }
    else if (e < NX + 2 * NW) { src = wk; dst = wqkb + NW;  off = e - NX - NW; }
    else                      { src = wv; dst = wvb;        off = e - NX - 2 * NW; }
    float4 f = *(const float4*)(src + off);
    uint32_t lo = ((uint32_t)f2bf_bits(f.y) << 16) | f2bf_bits(f.x);
    uint32_t hi = ((uint32_t)f2bf_bits(f.w) << 16) | f2bf_bits(f.z);
    *(uint2*)(dst + off) = make_uint2(lo, hi);
  }
}

// ---------------------------------------------------------------------------
// Legacy 128x128 2-phase gemm (kept for the small Vt projection only).
// ---------------------------------------------------------------------------
template <typename OUT_T>
__global__ __launch_bounds__(256)
void gemm_bt(const bf16_t* __restrict__ A, const bf16_t* __restrict__ B,
             OUT_T* __restrict__ C, int K, int lda, int ldb, int ldc,
             int64_t b_batch_stride, int bm_per_batch)
{
  __shared__ bf16_t As[2][128 * 32];
  __shared__ bf16_t Bs[2][128 * 32];
  const int tid  = threadIdx.x;
  const int wid  = tid >> 6;
  const int lane = tid & 63;
  const int wm = wid >> 1, wn = wid & 1;
  const int64_t bm = blockIdx.x;
  const int64_t bn = blockIdx.y;

  const bf16_t* Bb = B + (bm / bm_per_batch) * b_batch_stride;

  const int c0row = (wid * 2 + 0) * 16 + (lane >> 2);
  const int c1row = (wid * 2 + 1) * 16 + (lane >> 2);
  const int scol  = (lane & 3) * 8;

  const bf16_t* Ar0 = A  + (bm * 128 + c0row) * lda + scol;
  const bf16_t* Ar1 = A  + (bm * 128 + c1row) * lda + scol;
  const bf16_t* Br0 = Bb + (bn * 128 + c0row) * ldb + scol;
  const bf16_t* Br1 = Bb + (bn * 128 + c1row) * ldb + scol;

  const int ad0 = (wid * 2 + 0) * 512;
  const int ad1 = (wid * 2 + 1) * 512;

  const int frow = lane & 15;
  const int fk   = (lane >> 4) * 8;
  const int aoff = (wm * 64 + frow) * 32 + fk;
  const int boff = (wn * 64 + frow) * 32 + fk;

  f32x4 acc[4][4];
  #pragma unroll
  for (int m = 0; m < 4; m++)
    #pragma unroll
    for (int n = 0; n < 4; n++) acc[m][n] = f32x4{0.f, 0.f, 0.f, 0.f};

  auto stage = [&](int buf, int k0) {
    __builtin_amdgcn_global_load_lds((const gv_t*)(Ar0 + k0),
                                     (lv_t*)(&As[buf][ad0]), 16, 0, 0);
    __builtin_amdgcn_global_load_lds((const gv_t*)(Ar1 + k0),
                                     (lv_t*)(&As[buf][ad1]), 16, 0, 0);
    __builtin_amdgcn_global_load_lds((const gv_t*)(Br0 + k0),
                                     (lv_t*)(&Bs[buf][ad0]), 16, 0, 0);
    __builtin_amdgcn_global_load_lds((const gv_t*)(Br1 + k0),
                                     (lv_t*)(&Bs[buf][ad1]), 16, 0, 0);
  };

  stage(0, 0);
  __syncthreads();
  int cur = 0;
  for (int k0 = 0; k0 < K; k0 += 32) {
    if (k0 + 32 < K) stage(cur ^ 1, k0 + 32);

    bf16x8 af[4], bfr[4];
    #pragma unroll
    for (int m = 0; m < 4; m++)
      af[m] = *(const bf16x8*)(&As[cur][aoff + m * 16 * 32]);
    #pragma unroll
    for (int n = 0; n < 4; n++)
      bfr[n] = *(const bf16x8*)(&Bs[cur][boff + n * 16 * 32]);
    #pragma unroll
    for (int m = 0; m < 4; m++)
      #pragma unroll
      for (int n = 0; n < 4; n++)
        acc[m][n] = __builtin_amdgcn_mfma_f32_16x16x32_bf16(af[m], bfr[n],
                                                            acc[m][n], 0, 0, 0);
    __syncthreads();
    cur ^= 1;
  }

  const int crow = (lane >> 4) * 4;
  const int ccol = lane & 15;
  #pragma unroll
  for (int m = 0; m < 4; m++)
    #pragma unroll
    for (int n = 0; n < 4; n++)
      #pragma unroll
      for (int j = 0; j < 4; j++) {
        int64_t row = bm * 128 + wm * 64 + m * 16 + crow + j;
        int64_t col = bn * 128 + wn * 64 + n * 16 + ccol;
        storeC(&C[row * ldc + col], acc[m][n][j]);
      }
}

// ---------------------------------------------------------------------------
// 256x256 bf16 GEMM, 1-barrier-per-K-tile pipelined loop (R8 — best) +
// XCD-aware block remap (R13). Per K-tile: issue all 24 ds_reads (k0 first),
// issue next tile's 8 stages -> other buf, 64 MFMA with compiler-counted
// lgkm waits, vmcnt(0), one s_barrier.
// ---------------------------------------------------------------------------
template <typename OUT_T, typename OUT2_T>
__global__ __launch_bounds__(512, 2)
void gemm256(const bf16_t* __restrict__ A, const bf16_t* __restrict__ B,
             OUT_T* __restrict__ C0, OUT2_T* __restrict__ C1,
             int K, int lda, int ldb, int ldc,
             int64_t b_batch_stride, int bm_per_batch,
             int64_t za_off, int64_t zb_off)
{
  __shared__ bf16_t As[2][256][64];
  __shared__ bf16_t Bs[2][256][64];

  const int tid  = threadIdx.x;
  const int wid  = tid >> 6;     // 0..7
  const int lane = tid & 63;
  const int wm = wid >> 2;
  const int wn = wid & 3;
  int64_t bm, bn;
  xcd_remap(bm, bn);
  const int z = blockIdx.z;

  const bf16_t* Ap = A + (int64_t)z * za_off;
  const bf16_t* Bp = B + (bm / bm_per_batch) * b_batch_stride
                       + (int64_t)z * zb_off;

  const int srow  = tid >> 3;          // 0..63
  const int sslot = (tid & 7) ^ (srow & 7);
  const int64_t lda64 = lda, ldb64 = ldb;
  const bf16_t* Ag = Ap + (bm * 256 + srow) * lda64 + sslot * 8;
  const bf16_t* Bg = Bp + (bn * 256 + srow) * ldb64 + sslot * 8;

  auto stageA = [&](int buf, int t, int q) {
    const bf16_t* src = Ag + (int64_t)(q * 64) * lda64 + t * 64;
    char* dst = (char*)&As[buf][0][0] + (q * 64 + wid * 8) * 128;
    __builtin_amdgcn_global_load_lds((const gv_t*)src, (lv_t*)dst, 16, 0, 0);
  };
  auto stageB = [&](int buf, int t, int q) {
    const bf16_t* src = Bg + (int64_t)(q * 64) * ldb64 + t * 64;
    char* dst = (char*)&Bs[buf][0][0] + (q * 64 + wid * 8) * 128;
    __builtin_amdgcn_global_load_lds((const gv_t*)src, (lv_t*)dst, 16, 0, 0);
  };

  const int frow   = lane & 15;
  const int fcol16 = lane >> 4;
  const int xorv   = (lane & 7) << 4;
  const int ck0 = (fcol16 * 16) ^ xorv;
  const int ck1 = (64 + fcol16 * 16) ^ xorv;
  const int arowb = (wm * 128 + frow) * 128;
  const int browb = (wn * 64  + frow) * 128;

  f32x4 acc[8][4];
  #pragma unroll
  for (int m = 0; m < 8; m++)
    #pragma unroll
    for (int n = 0; n < 4; n++) acc[m][n] = f32x4{0.f, 0.f, 0.f, 0.f};

  const int NT = K >> 6;

  #pragma unroll
  for (int q = 0; q < 4; q++) stageA(0, 0, q);
  #pragma unroll
  for (int q = 0; q < 4; q++) stageB(0, 0, q);
  asm volatile("s_waitcnt vmcnt(0)" ::: "memory");
  __builtin_amdgcn_s_barrier();
  __builtin_amdgcn_sched_barrier(0);

  bf16x8 a[8][2], bb[4][2];

  for (int g = 0; g < NT; ++g) {
    const int buf = g & 1;
    const char* lA = (const char*)&As[buf][0][0];
    const char* lB = (const char*)&Bs[buf][0][0];

    #pragma unroll
    for (int m = 0; m < 8; m++)
      a[m][0] = *(const bf16x8*)(lA + arowb + m * 2048 + ck0);
    #pragma unroll
    for (int n = 0; n < 4; n++)
      bb[n][0] = *(const bf16x8*)(lB + browb + n * 2048 + ck0);
    #pragma unroll
    for (int m = 0; m < 8; m++)
      a[m][1] = *(const bf16x8*)(lA + arowb + m * 2048 + ck1);
    #pragma unroll
    for (int n = 0; n < 4; n++)
      bb[n][1] = *(const bf16x8*)(lB + browb + n * 2048 + ck1);

    if (g + 1 < NT) {
      #pragma unroll
      for (int q = 0; q < 4; q++) stageA(buf ^ 1, g + 1, q);
      #pragma unroll
      for (int q = 0; q < 4; q++) stageB(buf ^ 1, g + 1, q);
    }

    __builtin_amdgcn_s_setprio(1);
    #pragma unroll
    for (int k = 0; k < 2; k++)
      #pragma unroll
      for (int m = 0; m < 8; m++)
        #pragma unroll
        for (int n = 0; n < 4; n++)
          acc[m][n] = __builtin_amdgcn_mfma_f32_16x16x32_bf16(
              a[m][k], bb[n][k], acc[m][n], 0, 0, 0);
    __builtin_amdgcn_s_setprio(0);

    asm volatile("s_waitcnt vmcnt(0)" ::: "memory");
    __builtin_amdgcn_s_barrier();
    __builtin_amdgcn_sched_barrier(0);
  }

  const int crow = (lane >> 4) * 4;
  const int ccol = lane & 15;
  if (z == 0) {
    #pragma unroll
    for (int m = 0; m < 8; m++)
      #pragma unroll
      for (int n = 0; n < 4; n++)
        #pragma unroll
        for (int j = 0; j < 4; j++) {
          int64_t row = bm * 256 + wm * 128 + m * 16 + crow + j;
          int64_t col = bn * 256 + wn * 64 + n * 16 + ccol;
          storeC(&C0[row * (int64_t)ldc + col], acc[m][n][j]);
        }
  } else {
    #pragma unroll
    for (int m = 0; m < 8; m++)
      #pragma unroll
      for (int n = 0; n < 4; n++)
        #pragma unroll
        for (int j = 0; j < 4; j++) {
          int64_t row = bm * 256 + wm * 128 + m * 16 + crow + j;
          int64_t col = bn * 256 + wn * 64 + n * 16 + ccol;
          storeC(&C1[row * (int64_t)ldc + col], acc[m][n][j]);
        }
  }
}

// ---------------------------------------------------------------------------
// 128x128 bf16 GEMM, R8 choreography, 2 blocks/CU (R10 kernel, verified) +
// XCD remap. Used for PV (N=1024 -> grid 64x8 = 512 blocks, no split-K).
// ---------------------------------------------------------------------------
template <typename OUT_T, typename OUT2_T>
__global__ __launch_bounds__(256, 2)
void gemm128(const bf16_t* __restrict__ A, const bf16_t* __restrict__ B,
             OUT_T* __restrict__ C0, OUT2_T* __restrict__ C1,
             int K, int lda, int ldb, int ldc,
             int64_t b_batch_stride, int bm_per_batch,
             int64_t za_off, int64_t zb_off)
{
  __shared__ bf16_t As[2][128][64];
  __shared__ bf16_t Bs[2][128][64];

  const int tid  = threadIdx.x;
  const int wid  = tid >> 6;
  const int lane = tid & 63;
  const int wm = wid >> 1;
  const int wn = wid & 1;
  int64_t bm, bn;
  xcd_remap(bm, bn);
  const int z = blockIdx.z;

  const bf16_t* Ap = A + (int64_t)z * za_off;
  const bf16_t* Bp = B + (bm / bm_per_batch) * b_batch_stride
                       + (int64_t)z * zb_off;

  const int srow  = tid >> 3;
  const int sslot = (tid & 7) ^ (srow & 7);
  const int64_t lda64 = lda, ldb64 = ldb;
  const bf16_t* Ag = Ap + (bm * 128 + srow) * lda64 + sslot * 8;
  const bf16_t* Bg = Bp + (bn * 128 + srow) * ldb64 + sslot * 8;

  auto stageA = [&](int buf, int t, int q) {
    const bf16_t* src = Ag + (int64_t)(q * 32) * lda64 + t * 64;
    char* dst = (char*)&As[buf][0][0] + (q * 32 + wid * 8) * 128;
    __builtin_amdgcn_global_load_lds((const gv_t*)src, (lv_t*)dst, 16, 0, 0);
  };
  auto stageB = [&](int buf, int t, int q) {
    const bf16_t* src = Bg + (int64_t)(q * 32) * ldb64 + t * 64;
    char* dst = (char*)&Bs[buf][0][0] + (q * 32 + wid * 8) * 128;
    __builtin_amdgcn_global_load_lds((const gv_t*)src, (lv_t*)dst, 16, 0, 0);
  };

  const int frow   = lane & 15;
  const int fcol16 = lane >> 4;
  const int xorv   = (lane & 7) << 4;
  const int ck0 = (fcol16 * 16) ^ xorv;
  const int ck1 = (64 + fcol16 * 16) ^ xorv;
  const int arowb = (wm * 64 + frow) * 128;
  const int browb = (wn * 64 + frow) * 128;

  f32x4 acc[4][4];
  #pragma unroll
  for (int m = 0; m < 4; m++)
    #pragma unroll
    for (int n = 0; n < 4; n++) acc[m][n] = f32x4{0.f, 0.f, 0.f, 0.f};

  const int NT = K >> 6;

  stageA(0, 0, 0); stageA(0, 0, 1); stageA(0, 0, 2); stageA(0, 0, 3);
  stageB(0, 0, 0); stageB(0, 0, 1); stageB(0, 0, 2); stageB(0, 0, 3);
  asm volatile("s_waitcnt vmcnt(0)" ::: "memory");
  __builtin_amdgcn_s_barrier();
  __builtin_amdgcn_sched_barrier(0);

  bf16x8 a[4][2], bb[4][2];

  for (int g = 0; g < NT; ++g) {
    const int buf = g & 1;
    const char* lA = (const char*)&As[buf][0][0];
    const char* lB = (const char*)&Bs[buf][0][0];

    #pragma unroll
    for (int m = 0; m < 4; m++)
      a[m][0] = *(const bf16x8*)(lA + arowb + m * 2048 + ck0);
    #pragma unroll
    for (int n = 0; n < 4; n++)
      bb[n][0] = *(const bf16x8*)(lB + browb + n * 2048 + ck0);
    #pragma unroll
    for (int m = 0; m < 4; m++)
      a[m][1] = *(const bf16x8*)(lA + arowb + m * 2048 + ck1);
    #pragma unroll
    for (int n = 0; n < 4; n++)
      bb[n][1] = *(const bf16x8*)(lB + browb + n * 2048 + ck1);

    if (g + 1 < NT) {
      stageA(buf ^ 1, g + 1, 0); stageA(buf ^ 1, g + 1, 1);
      stageA(buf ^ 1, g + 1, 2); stageA(buf ^ 1, g + 1, 3);
      stageB(buf ^ 1, g + 1, 0); stageB(buf ^ 1, g + 1, 1);
      stageB(buf ^ 1, g + 1, 2); stageB(buf ^ 1, g + 1, 3);
    }

    __builtin_amdgcn_s_setprio(1);
    #pragma unroll
    for (int k = 0; k < 2; k++)
      #pragma unroll
      for (int m = 0; m < 4; m++)
        #pragma unroll
        for (int n = 0; n < 4; n++)
          acc[m][n] = __builtin_amdgcn_mfma_f32_16x16x32_bf16(
              a[m][k], bb[n][k], acc[m][n], 0, 0, 0);
    __builtin_amdgcn_s_setprio(0);

    asm volatile("s_waitcnt vmcnt(0)" ::: "memory");
    __builtin_amdgcn_s_barrier();
    __builtin_amdgcn_sched_barrier(0);
  }

  const int crow = (lane >> 4) * 4;
  const int ccol = lane & 15;
  if (z == 0) {
    #pragma unroll
    for (int m = 0; m < 4; m++)
      #pragma unroll
      for (int n = 0; n < 4; n++)
        #pragma unroll
        for (int j = 0; j < 4; j++) {
          int64_t row = bm * 128 + wm * 64 + m * 16 + crow + j;
          int64_t col = bn * 128 + wn * 64 + n * 16 + ccol;
          storeC(&C0[row * (int64_t)ldc + col], acc[m][n][j]);
        }
  } else {
    #pragma unroll
    for (int m = 0; m < 4; m++)
      #pragma unroll
      for (int n = 0; n < 4; n++)
        #pragma unroll
        for (int j = 0; j < 4; j++) {
          int64_t row = bm * 128 + wm * 64 + m * 16 + crow + j;
          int64_t col = bn * 128 + wn * 64 + n * 16 + ccol;
          storeC(&C1[row * (int64_t)ldc + col], acc[m][n][j]);
        }
  }
}

// ---------------------------------------------------------------------------
// Row softmax IN PLACE: fp16 raw scores [rows x 4096] -> normalized bf16 P.
// ---------------------------------------------------------------------------
__global__ __launch_bounds__(256)
void softmax_rows(__half* __restrict__ SP)
{
  const int64_t row = blockIdx.x;
  __half* s = SP + row * 4096;
  bf16_t* p = (bf16_t*)s;
  const int tid = threadIdx.x;
  const float scale = 0.03125f;  // 1/sqrt(1024)

  float v[16];
  float vmax = -3.4e38f;
  #pragma unroll
  for (int i = 0; i < 4; i++) {
    uint2 raw = *(const uint2*)(s + i * 1024 + tid * 4);
    __half2 h01 = __builtin_bit_cast(__half2, raw.x);
    __half2 h23 = __builtin_bit_cast(__half2, raw.y);
    float2 f01 = __half22float2(h01);
    float2 f23 = __half22float2(h23);
    v[i * 4 + 0] = f01.x * scale;
    v[i * 4 + 1] = f01.y * scale;
    v[i * 4 + 2] = f23.x * scale;
    v[i * 4 + 3] = f23.y * scale;
    vmax = fmaxf(vmax, fmaxf(fmaxf(v[i*4+0], v[i*4+1]),
                             fmaxf(v[i*4+2], v[i*4+3])));
  }
  #pragma unroll
  for (int o = 32; o > 0; o >>= 1) vmax = fmaxf(vmax, __shfl_xor(vmax, o));
  __shared__ float redm[4];
  __shared__ float reds[4];
  if ((tid & 63) == 0) redm[tid >> 6] = vmax;
  __syncthreads();
  vmax = fmaxf(fmaxf(redm[0], redm[1]), fmaxf(redm[2], redm[3]));

  float lsum = 0.f;
  #pragma unroll
  for (int i = 0; i < 16; i++) {
    v[i] = __expf(v[i] - vmax);
    lsum += v[i];
  }
  #pragma unroll
  for (int o = 32; o > 0; o >>= 1) lsum += __shfl_xor(lsum, o);
  if ((tid & 63) == 0) reds[tid >> 6] = lsum;
  __syncthreads();
  lsum = (reds[0] + reds[1]) + (reds[2] + reds[3]);
  const float inv = 1.0f / lsum;

  #pragma unroll
  for (int i = 0; i < 4; i++) {
    uint32_t lo = ((uint32_t)f2bf_bits(v[i*4+1] * inv) << 16) | f2bf_bits(v[i*4+0] * inv);
    uint32_t hi = ((uint32_t)f2bf_bits(v[i*4+3] * inv) << 16) | f2bf_bits(v[i*4+2] * inv);
    *(uint2*)(p + i * 1024 + tid * 4) = make_uint2(lo, hi);
  }
}

// ---------------------------------------------------------------------------
// ws layout (112 MiB):
//   [0,   64M): S/P fp16->bf16 [8192 x 4096]
//               overlapped early: xb [0,16M), wqkb [16M,20M), wvb [20M,22M)
//   [64M, 96M): qk bf16 [8192 x 2048] (Q|K)
//   [96M,112M): vt bf16 [1024 x 8192]
// ---------------------------------------------------------------------------
extern "C" void kernel_launch(void* const* d_in, const int* in_sizes, int n_in,
                              void* d_out, int out_size, void* d_ws, size_t ws_size,
                              hipStream_t stream) {
  const float* x  = (const float*)d_in[0];
  const float* wq = (const float*)d_in[1];
  const float* wk = (const float*)d_in[2];
  const float* wv = (const float*)d_in[3];
  float* out = (float*)d_out;

  char* ws = (char*)d_ws;
  bf16_t* xb   = (bf16_t*)ws;
  bf16_t* wqkb = (bf16_t*)(ws + (16LL << 20));
  bf16_t* wvb  = (bf16_t*)(ws + (20LL << 20));
  __half* S    = (__half*)ws;
  bf16_t* qk   = (bf16_t*)(ws + (64LL << 20));
  bf16_t* vt   = (bf16_t*)(ws + (96LL << 20));

  const int NO_BATCH = 1 << 30;

  convert_all<<<2048, 256, 0, stream>>>(x, wq, wk, wv, xb, wqkb, wvb);

  // qk[8192 x 2048] = xb * wqkb^T
  gemm256<bf16_t, bf16_t><<<dim3(32, 8, 1), 512, 0, stream>>>(
      xb, wqkb, qk, qk, 1024, 1024, 1024, 2048, 0, NO_BATCH, 0, 0);

  // vt[1024 x 8192] = wvb * xb^T
  gemm_bt<bf16_t><<<dim3(8, 64), 256, 0, stream>>>(
      wvb, xb, vt, 1024, 1024, 1024, 8192, 0, NO_BATCH);

  // S[8192 x 4096] = Q * K_b^T (raw fp16), batch b = bm/16
  gemm256<__half, __half><<<dim3(32, 16, 1), 512, 0, stream>>>(
      qk, qk + 1024, S, S, 1024, 2048, 2048, 4096, 4096LL * 2048, 16, 0, 0);

  softmax_rows<<<8192, 256, 0, stream>>>(S);

  // out[8192 x 1024] = P * V_b^T (no split-K, direct f32), batch b = bm/32
  gemm128<float, float><<<dim3(64, 8, 1), 256, 0, stream>>>(
      (const bf16_t*)S, vt, out, out, 4096, 4096, 8192, 1024,
      4096, 32, 0, 0);
}